// Round 3
// baseline (864.391 us; speedup 1.0000x reference)
//
#include <hip/hip_runtime.h>
#include <stdint.h>
#include <math.h>

typedef unsigned short u16;
typedef __attribute__((ext_vector_type(8))) short short8;
typedef __attribute__((ext_vector_type(4))) float floatx4;

__device__ __forceinline__ u16 f32_to_bf16(float f) {
    union { float f; uint32_t u; } v; v.f = f;
    uint32_t r = v.u + 0x7FFF + ((v.u >> 16) & 1);   // RTNE
    return (u16)(r >> 16);
}
__device__ __forceinline__ float bf16_to_f32(u16 h) {
    union { uint32_t u; float f; } v; v.u = ((uint32_t)h) << 16; return v.f;
}

__device__ __forceinline__ void gl_lds16(const u16* g, u16* l) {
    __builtin_amdgcn_global_load_lds(
        (const __attribute__((address_space(1))) void*)g,
        (__attribute__((address_space(3))) void*)l, 16, 0, 0);
}

// ---------------- prep kernels ----------------

__global__ void split_kernel(const float4* __restrict__ x, ushort4* __restrict__ hi,
                             ushort4* __restrict__ lo, long n4) {
    long i = (long)blockIdx.x * blockDim.x + threadIdx.x;
    if (i >= n4) return;
    float4 v = x[i];
    ushort4 h, l;
    h.x = f32_to_bf16(v.x); l.x = f32_to_bf16(v.x - bf16_to_f32(h.x));
    h.y = f32_to_bf16(v.y); l.y = f32_to_bf16(v.y - bf16_to_f32(h.y));
    h.z = f32_to_bf16(v.z); l.z = f32_to_bf16(v.z - bf16_to_f32(h.z));
    h.w = f32_to_bf16(v.w); l.w = f32_to_bf16(v.w - bf16_to_f32(h.w));
    hi[i] = h; lo[i] = l;
}

__global__ void conv_kernel(const float4* __restrict__ x, ushort4* __restrict__ hi, long n4) {
    long i = (long)blockIdx.x * blockDim.x + threadIdx.x;
    if (i >= n4) return;
    float4 v = x[i];
    ushort4 h;
    h.x = f32_to_bf16(v.x); h.y = f32_to_bf16(v.y);
    h.z = f32_to_bf16(v.z); h.w = f32_to_bf16(v.w);
    hi[i] = h;
}

// bf16 [R][C] -> bf16 [C][R]; pad 34 (68 B = 17 banks, odd -> conflict-free)
__global__ void transpose_u16(const u16* __restrict__ src, u16* __restrict__ dst,
                              int R, int C) {
    __shared__ u16 tile[32][34];
    long base = (long)blockIdx.z * R * C;
    int c0 = blockIdx.x * 32, r0 = blockIdx.y * 32;
    #pragma unroll
    for (int i = threadIdx.y; i < 32; i += 8)
        tile[i][threadIdx.x] = src[base + (long)(r0 + i) * C + c0 + threadIdx.x];
    __syncthreads();
    #pragma unroll
    for (int i = threadIdx.y; i < 32; i += 8)
        dst[base + (long)(c0 + i) * R + r0 + threadIdx.x] = tile[threadIdx.x][i];
}

// softmax over rows of (data [+ q1 + q2]); writes fp32 back to data, bf16 to outb
template <int VPT, int NS>
__global__ void softmax_rows(float* __restrict__ data, const float* __restrict__ q1,
                             const float* __restrict__ q2, u16* __restrict__ outb) {
    int row = blockIdx.x * 4 + (threadIdx.x >> 6);
    int lane = threadIdx.x & 63;
    long base = (long)row * (VPT * 64) + lane;
    float v[VPT];
    #pragma unroll
    for (int i = 0; i < VPT; ++i) {
        v[i] = data[base + i * 64];
        if (NS == 3) v[i] += q1[base + i * 64] + q2[base + i * 64];
    }
    float m = v[0];
    #pragma unroll
    for (int i = 1; i < VPT; ++i) m = fmaxf(m, v[i]);
    #pragma unroll
    for (int off = 32; off > 0; off >>= 1) m = fmaxf(m, __shfl_xor(m, off, 64));
    float s = 0.f;
    #pragma unroll
    for (int i = 0; i < VPT; ++i) { v[i] = __expf(v[i] - m); s += v[i]; }
    #pragma unroll
    for (int off = 32; off > 0; off >>= 1) s += __shfl_xor(s, off, 64);
    float inv = 1.0f / s;
    #pragma unroll
    for (int i = 0; i < VPT; ++i) {
        float r = v[i] * inv;
        data[base + i * 64] = r;
        outb[base + i * 64] = f32_to_bf16(r);
    }
}

// ---------------- GEMM (C = A * B^T), bf16 MFMA, K-segmented ----------------
// XOR-swizzled LDS (R1->R2: conflicts 4.7e7 -> 0, keep).
// zsplit=1: segment index taken from blockIdx.z/nbatch -> 3x grid parallelism,
// per-seg fp32 partials to Cfs[seg] (summed later in softmax). zsplit=0: classic
// in-register accumulation over nseg segments.
// mode 0: store fp32 | mode 1: store bf16 | mode 2: store fp32 tanh(acc+bias[col])
struct GemmP {
    const u16* A[3];
    const u16* B[3];
    float* Cfs[3];
    long strideAb, strideBb, strideCb;
    int bdiv, nseg, Kper, lda, ldb, ldc, mode;
    int zsplit, nbatch;
    float* Cf; u16* Cb; const float* bias;
};

__global__ __launch_bounds__(256) void gemm_bt(GemmP p) {
    __shared__ u16 As[128 * 64];
    __shared__ u16 Bs[128 * 64];
    const int tid  = threadIdx.x;
    const int lane = tid & 63;
    const int wave = tid >> 6;
    const int quad = lane >> 4;
    const int l15  = lane & 15;
    const int wm = (wave & 1) * 64;
    const int wn = (wave >> 1) * 64;
    const int n0 = blockIdx.x * 128;
    const int m0 = blockIdx.y * 128;

    int bz = blockIdx.z;
    int seg0 = 0, nseg = p.nseg;
    float* Cf = p.Cf;
    if (p.zsplit) {
        seg0 = bz / p.nbatch;
        bz   = bz % p.nbatch;
        nseg = 1;
        Cf   = p.Cfs[seg0];
    }

    const int stg_r8 = tid >> 3;
    const int stg_c  = ((tid & 7) ^ (stg_r8 & 7)) * 8;
    const int xorl   = l15 & 7;

    floatx4 acc[4][4];
    #pragma unroll
    for (int i = 0; i < 4; ++i)
        #pragma unroll
        for (int j = 0; j < 4; ++j)
            acc[i][j] = (floatx4){0.f, 0.f, 0.f, 0.f};

    const long aoff = (long)bz * p.strideAb;
    const long boff = (long)(bz / p.bdiv) * p.strideBb;

    for (int seg = seg0; seg < seg0 + nseg; ++seg) {
        const u16* Ag = p.A[seg] + aoff + (long)m0 * p.lda;
        const u16* Bg = p.B[seg] + boff + (long)n0 * p.ldb;
        for (int k0 = 0; k0 < p.Kper; k0 += 64) {
            __syncthreads();
            #pragma unroll
            for (int i = 0; i < 4; ++i) {
                const int r = i * 32 + stg_r8;
                gl_lds16(Ag + (long)r * p.lda + k0 + stg_c, &As[(i * 256 + tid) * 8]);
            }
            #pragma unroll
            for (int i = 0; i < 4; ++i) {
                const int r = i * 32 + stg_r8;
                gl_lds16(Bg + (long)r * p.ldb + k0 + stg_c, &Bs[(i * 256 + tid) * 8]);
            }
            __syncthreads();
            #pragma unroll
            for (int kk = 0; kk < 2; ++kk) {
                const int cs = ((kk * 4 + quad) ^ xorl) * 8;
                short8 af[4], bfr[4];
                #pragma unroll
                for (int i = 0; i < 4; ++i)
                    af[i] = *(const short8*)&As[(wm + i * 16 + l15) * 64 + cs];
                #pragma unroll
                for (int i = 0; i < 4; ++i)
                    bfr[i] = *(const short8*)&Bs[(wn + i * 16 + l15) * 64 + cs];
                #pragma unroll
                for (int mi = 0; mi < 4; ++mi)
                    #pragma unroll
                    for (int ni = 0; ni < 4; ++ni)
                        acc[mi][ni] = __builtin_amdgcn_mfma_f32_16x16x32_bf16(
                            af[mi], bfr[ni], acc[mi][ni], 0, 0, 0);
            }
        }
    }

    const long coff = (long)bz * p.strideCb;
    const int rb = m0 + wm + quad * 4;
    const int cbase = n0 + wn + l15;
    if (p.mode == 2) {
        #pragma unroll
        for (int ni = 0; ni < 4; ++ni) {
            const float bv = p.bias[cbase + ni * 16];
            #pragma unroll
            for (int mi = 0; mi < 4; ++mi)
                #pragma unroll
                for (int j = 0; j < 4; ++j)
                    Cf[coff + (long)(rb + mi * 16 + j) * p.ldc + cbase + ni * 16] =
                        tanhf(acc[mi][ni][j] + bv);
        }
    } else if (p.mode == 0) {
        #pragma unroll
        for (int ni = 0; ni < 4; ++ni)
            #pragma unroll
            for (int mi = 0; mi < 4; ++mi)
                #pragma unroll
                for (int j = 0; j < 4; ++j)
                    Cf[coff + (long)(rb + mi * 16 + j) * p.ldc + cbase + ni * 16] =
                        acc[mi][ni][j];
    } else {
        #pragma unroll
        for (int ni = 0; ni < 4; ++ni)
            #pragma unroll
            for (int mi = 0; mi < 4; ++mi)
                #pragma unroll
                for (int j = 0; j < 4; ++j)
                    p.Cb[coff + (long)(rb + mi * 16 + j) * p.ldc + cbase + ni * 16] =
                        f32_to_bf16(acc[mi][ni][j]);
    }
}

// ---------------- host ----------------
extern "C" void kernel_launch(void* const* d_in, const int* in_sizes, int n_in,
                              void* d_out, int out_size, void* d_ws, size_t ws_size,
                              hipStream_t stream) {
    const int BT = 80, L = 256, S = 512, H = 1024;
    const long NO    = (long)BT * L * H;   // 20971520
    const long NC1   = (long)8 * S * H;    // 4194304
    const long NW    = (long)H * 3 * H;    // 3145728
    const long NEXA  = (long)BT * L * L;   // 5242880
    const long NSETA = (long)BT * L * S;   // 10485760

    const float* X    = (const float*)d_in[0];
    const float* C0   = (const float*)d_in[1];
    const float* C1   = (const float*)d_in[2];
    const float* Wf   = (const float*)d_in[4];
    const float* bias = (const float*)d_in[5];

    float* out  = (float*)d_out;
    float* exa  = out + NO;
    float* seta = exa + NEXA;

    char* wsb = (char*)d_ws;
    size_t off = 0;
    auto alloc = [&](long nbytes) -> void* {
        void* p = (void*)(wsb + off);
        off += ((size_t)nbytes + 255) & ~(size_t)255;
        return p;
    };
    u16* Xhi  = (u16*)alloc(NO * 2);
    u16* Xlo  = (u16*)alloc(NO * 2);
    u16* C0hi = (u16*)alloc(NO * 2);
    u16* C0lo = (u16*)alloc(NO * 2);
    u16* C1hi = (u16*)alloc(NC1 * 2);
    u16* C1lo = (u16*)alloc(NC1 * 2);
    u16* Wb   = (u16*)alloc(NW * 2);
    u16* exab = (u16*)alloc(NEXA * 2);
    u16* setab= (u16*)alloc(NSETA * 2);
    size_t base_off = off;
    // seg-split partials: P1 (2x NEXA fp32) for GEMM1; GEMM2 reuses that region
    // (P2a) + one more NSETA fp32 (P2b). Lifetimes: P1 dead after softmax1.
    float* P1a = (float*)alloc(NEXA * 4);
    float* P1b = (float*)alloc(NEXA * 4);
    float* P2b = (float*)alloc(NSETA * 4);
    float* P2a = P1a;  // 2*NEXA*4 == NSETA*4 bytes, exact fit
    const bool full = (off <= ws_size);
    (void)base_off;
    // aliases (lifetimes disjoint by launch order):
    u16* C0T = C0lo;   // written after GEMM1, read by GEMM3
    u16* C1T = C1lo;   // written after GEMM2, read by GEMM4
    u16* exc = Xlo;    // written by GEMM3 (Xlo last read in GEMM2)
    u16* setc = C0hi;  // written by GEMM4 (C0hi last read in GEMM2)

    // --- prep ---
    split_kernel<<<(int)(NO / 4 / 256), 256, 0, stream>>>((const float4*)X, (ushort4*)Xhi, (ushort4*)Xlo, NO / 4);
    split_kernel<<<(int)(NO / 4 / 256), 256, 0, stream>>>((const float4*)C0, (ushort4*)C0hi, (ushort4*)C0lo, NO / 4);
    split_kernel<<<(int)(NC1 / 4 / 256), 256, 0, stream>>>((const float4*)C1, (ushort4*)C1hi, (ushort4*)C1lo, NC1 / 4);
    conv_kernel<<<(int)(NW / 4 / 256), 256, 0, stream>>>((const float4*)Wf, (ushort4*)Wb, NW / 4);

    // --- GEMM1: ex logits = X @ C0^T (3-pass split) ---
    {
        GemmP p{};
        p.A[0] = Xhi;  p.A[1] = Xlo;  p.A[2] = Xhi;
        p.B[0] = C0hi; p.B[1] = C0hi; p.B[2] = C0lo;
        p.strideAb = (long)L * H; p.strideBb = (long)L * H; p.strideCb = (long)L * L;
        p.bdiv = 1; p.nseg = 3; p.Kper = H; p.lda = H; p.ldb = H; p.ldc = L; p.mode = 0;
        if (full) {
            p.zsplit = 1; p.nbatch = BT;
            p.Cfs[0] = exa; p.Cfs[1] = P1a; p.Cfs[2] = P1b;
            gemm_bt<<<dim3(L / 128, L / 128, 3 * BT), 256, 0, stream>>>(p);
            softmax_rows<4, 3><<<BT * L / 4, 256, 0, stream>>>(exa, P1a, P1b, exab);
        } else {
            p.Cf = exa;
            gemm_bt<<<dim3(L / 128, L / 128, BT), 256, 0, stream>>>(p);
            softmax_rows<4, 1><<<BT * L / 4, 256, 0, stream>>>(exa, nullptr, nullptr, exab);
        }
    }

    // --- GEMM2: set logits = X @ set_ctx^T (3-pass split) ---
    {
        GemmP p{};
        p.A[0] = Xhi;  p.A[1] = Xlo;  p.A[2] = Xhi;
        p.B[0] = C1hi; p.B[1] = C1hi; p.B[2] = C1lo;
        p.strideAb = (long)L * H; p.strideBb = (long)S * H; p.strideCb = (long)L * S;
        p.bdiv = 10; p.nseg = 3; p.Kper = H; p.lda = H; p.ldb = H; p.ldc = S; p.mode = 0;
        if (full) {
            p.zsplit = 1; p.nbatch = BT;
            p.Cfs[0] = seta; p.Cfs[1] = P2a; p.Cfs[2] = P2b;
            gemm_bt<<<dim3(S / 128, L / 128, 3 * BT), 256, 0, stream>>>(p);
            softmax_rows<8, 3><<<BT * L / 4, 256, 0, stream>>>(seta, P2a, P2b, setab);
        } else {
            p.Cf = seta;
            gemm_bt<<<dim3(S / 128, L / 128, BT), 256, 0, stream>>>(p);
            softmax_rows<8, 1><<<BT * L / 4, 256, 0, stream>>>(seta, nullptr, nullptr, setab);
        }
    }

    // --- transposes for PV B-operands (read bf16 hi, half the traffic of fp32) ---
    transpose_u16<<<dim3(H / 32, L / 32, BT), dim3(32, 8), 0, stream>>>(C0hi, C0T, L, H);
    transpose_u16<<<dim3(H / 32, S / 32, 8), dim3(32, 8), 0, stream>>>(C1hi, C1T, S, H);

    // --- GEMM3: ex_c = ex_attn @ C0 -> bf16 exc ---
    {
        GemmP p{};
        p.A[0] = exab; p.B[0] = C0T;
        p.strideAb = (long)L * L; p.strideBb = (long)H * L; p.strideCb = (long)L * H;
        p.bdiv = 1; p.nseg = 1; p.Kper = L; p.lda = L; p.ldb = L; p.ldc = H; p.mode = 1;
        p.Cb = exc;
        gemm_bt<<<dim3(H / 128, L / 128, BT), 256, 0, stream>>>(p);
    }
    // --- GEMM4: set_c = set_attn @ set_ctx -> bf16 setc ---
    {
        GemmP p{};
        p.A[0] = setab; p.B[0] = C1T;
        p.strideAb = (long)L * S; p.strideBb = (long)H * S; p.strideCb = (long)L * H;
        p.bdiv = 10; p.nseg = 1; p.Kper = S; p.lda = S; p.ldb = S; p.ldc = H; p.mode = 1;
        p.Cb = setc;
        gemm_bt<<<dim3(H / 128, L / 128, BT), 256, 0, stream>>>(p);
    }
    // --- GEMM5: out = tanh(concat(X, ex_c, set_c) @ W^T + b) ---
    {
        GemmP p{};
        p.A[0] = Xhi; p.A[1] = exc; p.A[2] = setc;
        p.B[0] = Wb;  p.B[1] = Wb + 1024; p.B[2] = Wb + 2048;
        p.strideAb = 0; p.strideBb = 0; p.strideCb = 0;
        p.bdiv = 1; p.nseg = 3; p.Kper = H; p.lda = H; p.ldb = 3 * H; p.ldc = H; p.mode = 2;
        p.Cf = out; p.bias = bias;
        gemm_bt<<<dim3(H / 128, BT * L / 128, 1), 256, 0, stream>>>(p);
    }
}

// Round 4
// 766.679 us; speedup vs baseline: 1.1274x; 1.1274x over previous
//
#include <hip/hip_runtime.h>
#include <stdint.h>
#include <math.h>

typedef unsigned short u16;
typedef __attribute__((ext_vector_type(8))) short short8;
typedef __attribute__((ext_vector_type(4))) float floatx4;

__device__ __forceinline__ u16 f32_to_bf16(float f) {
    union { float f; uint32_t u; } v; v.f = f;
    uint32_t r = v.u + 0x7FFF + ((v.u >> 16) & 1);   // RTNE
    return (u16)(r >> 16);
}
__device__ __forceinline__ float bf16_to_f32(u16 h) {
    union { uint32_t u; float f; } v; v.u = ((uint32_t)h) << 16; return v.f;
}

__device__ __forceinline__ void gl_lds16(const u16* g, u16* l) {
    __builtin_amdgcn_global_load_lds(
        (const __attribute__((address_space(1))) void*)g,
        (__attribute__((address_space(3))) void*)l, 16, 0, 0);
}

// ---------------- prep kernels ----------------

__global__ void split_kernel(const float4* __restrict__ x, ushort4* __restrict__ hi,
                             ushort4* __restrict__ lo, long n4) {
    long i = (long)blockIdx.x * blockDim.x + threadIdx.x;
    if (i >= n4) return;
    float4 v = x[i];
    ushort4 h, l;
    h.x = f32_to_bf16(v.x); l.x = f32_to_bf16(v.x - bf16_to_f32(h.x));
    h.y = f32_to_bf16(v.y); l.y = f32_to_bf16(v.y - bf16_to_f32(h.y));
    h.z = f32_to_bf16(v.z); l.z = f32_to_bf16(v.z - bf16_to_f32(h.z));
    h.w = f32_to_bf16(v.w); l.w = f32_to_bf16(v.w - bf16_to_f32(h.w));
    hi[i] = h; lo[i] = l;
}

__global__ void conv_kernel(const float4* __restrict__ x, ushort4* __restrict__ hi, long n4) {
    long i = (long)blockIdx.x * blockDim.x + threadIdx.x;
    if (i >= n4) return;
    float4 v = x[i];
    ushort4 h;
    h.x = f32_to_bf16(v.x); h.y = f32_to_bf16(v.y);
    h.z = f32_to_bf16(v.z); h.w = f32_to_bf16(v.w);
    hi[i] = h;
}

// bf16 [R][C] -> bf16 [C][R]; pad 34 (68 B = 17 banks, odd -> conflict-free)
__global__ void transpose_u16(const u16* __restrict__ src, u16* __restrict__ dst,
                              int R, int C) {
    __shared__ u16 tile[32][34];
    long base = (long)blockIdx.z * R * C;
    int c0 = blockIdx.x * 32, r0 = blockIdx.y * 32;
    #pragma unroll
    for (int i = threadIdx.y; i < 32; i += 8)
        tile[i][threadIdx.x] = src[base + (long)(r0 + i) * C + c0 + threadIdx.x];
    __syncthreads();
    #pragma unroll
    for (int i = threadIdx.y; i < 32; i += 8)
        dst[base + (long)(c0 + i) * R + r0 + threadIdx.x] = tile[threadIdx.x][i];
}

// in-place row softmax (fp32) + bf16 copy. one wave per row, 4 rows/block.
template <int VPT>
__global__ void softmax_rows(float* __restrict__ data, u16* __restrict__ outb) {
    int row = blockIdx.x * 4 + (threadIdx.x >> 6);
    int lane = threadIdx.x & 63;
    long base = (long)row * (VPT * 64) + lane;
    float v[VPT];
    #pragma unroll
    for (int i = 0; i < VPT; ++i) v[i] = data[base + i * 64];
    float m = v[0];
    #pragma unroll
    for (int i = 1; i < VPT; ++i) m = fmaxf(m, v[i]);
    #pragma unroll
    for (int off = 32; off > 0; off >>= 1) m = fmaxf(m, __shfl_xor(m, off, 64));
    float s = 0.f;
    #pragma unroll
    for (int i = 0; i < VPT; ++i) { v[i] = __expf(v[i] - m); s += v[i]; }
    #pragma unroll
    for (int off = 32; off > 0; off >>= 1) s += __shfl_xor(s, off, 64);
    float inv = 1.0f / s;
    #pragma unroll
    for (int i = 0; i < VPT; ++i) {
        float r = v[i] * inv;
        data[base + i * 64] = r;
        outb[base + i * 64] = f32_to_bf16(r);
    }
}

// ---------------- GEMM (C = A * B^T), bf16 MFMA, K-segmented ----------------
// XOR-swizzled LDS (R1->R2: bank conflicts 4.7e7 -> 0).
// 1-D grid + XCD-contiguous remap: hw assigns block f to XCD f%8; we give XCD x
// the contiguous tile range [x*T/8, (x+1)*T/8), decoded n-fastest so the gx
// n-tiles sharing an A m-tile run back-to-back on ONE XCD (A: 1 HBM fetch +
// gx-1 L2 hits; R3 evidence: without this, FETCH_SIZE was 4x ideal on GEMM5).
// Two-part N (nx1): tiles with n < nx1 use B/Cf/ldc/bdiv ("part 1"), others use
// B2/Cf2/ldc2/bdiv2 — lets GEMM1+GEMM2 (same A, same K) merge into one dispatch.
// mode 0: store fp32 | mode 1: store bf16 | mode 2: store fp32 tanh(acc+bias[col])
struct GemmP {
    const u16* A[3];
    const u16* B[3];
    const u16* B2[3];
    long strideAb, strideBb, strideB2b, strideCb, strideC2b;
    int bdiv, bdiv2, nseg, Kper, lda, ldb, ldb2, ldc, ldc2, mode;
    int gx, gy, nx1;
    float* Cf; float* Cf2; u16* Cb; const float* bias;
};

__global__ __launch_bounds__(256) void gemm_bt(GemmP p) {
    __shared__ u16 As[128 * 64];
    __shared__ u16 Bs[128 * 64];
    const int tid  = threadIdx.x;
    const int lane = tid & 63;
    const int wave = tid >> 6;
    const int quad = lane >> 4;
    const int l15  = lane & 15;
    const int wm = (wave & 1) * 64;
    const int wn = (wave >> 1) * 64;

    // XCD-contiguous remap (T multiple of 8 guaranteed by host)
    const int f  = blockIdx.x;
    const int Tx = gridDim.x >> 3;
    const int t  = (f & 7) * Tx + (f >> 3);
    const int n  = t % p.gx;
    const int r  = t / p.gx;
    const int m0 = (r % p.gy) * 128;
    const int bz = r / p.gy;

    const u16* Bsegs[3];
    int ldb, ldc, nn, bdv;
    long bstr, cstr;
    float* Cf;
    if (n < p.nx1) {
        Bsegs[0] = p.B[0]; Bsegs[1] = p.B[1]; Bsegs[2] = p.B[2];
        ldb = p.ldb; ldc = p.ldc; bstr = p.strideBb; cstr = p.strideCb;
        Cf = p.Cf; bdv = p.bdiv; nn = n;
    } else {
        Bsegs[0] = p.B2[0]; Bsegs[1] = p.B2[1]; Bsegs[2] = p.B2[2];
        ldb = p.ldb2; ldc = p.ldc2; bstr = p.strideB2b; cstr = p.strideC2b;
        Cf = p.Cf2; bdv = p.bdiv2; nn = n - p.nx1;
    }
    const int n0 = nn * 128;

    const int stg_r8 = tid >> 3;
    const int stg_c  = ((tid & 7) ^ (stg_r8 & 7)) * 8;
    const int xorl   = l15 & 7;

    floatx4 acc[4][4];
    #pragma unroll
    for (int i = 0; i < 4; ++i)
        #pragma unroll
        for (int j = 0; j < 4; ++j)
            acc[i][j] = (floatx4){0.f, 0.f, 0.f, 0.f};

    const long aoff = (long)bz * p.strideAb + (long)m0 * p.lda;
    const long boff = (long)(bz / bdv) * bstr + (long)n0 * ldb;

    for (int seg = 0; seg < p.nseg; ++seg) {
        const u16* Ag = p.A[seg] + aoff;
        const u16* Bg = Bsegs[seg] + boff;
        for (int k0 = 0; k0 < p.Kper; k0 += 64) {
            __syncthreads();
            #pragma unroll
            for (int i = 0; i < 4; ++i) {
                const int rr = i * 32 + stg_r8;
                gl_lds16(Ag + (long)rr * p.lda + k0 + stg_c, &As[(i * 256 + tid) * 8]);
            }
            #pragma unroll
            for (int i = 0; i < 4; ++i) {
                const int rr = i * 32 + stg_r8;
                gl_lds16(Bg + (long)rr * ldb + k0 + stg_c, &Bs[(i * 256 + tid) * 8]);
            }
            __syncthreads();
            #pragma unroll
            for (int kk = 0; kk < 2; ++kk) {
                const int cs = ((kk * 4 + quad) ^ xorl) * 8;
                short8 af[4], bfr[4];
                #pragma unroll
                for (int i = 0; i < 4; ++i)
                    af[i] = *(const short8*)&As[(wm + i * 16 + l15) * 64 + cs];
                #pragma unroll
                for (int i = 0; i < 4; ++i)
                    bfr[i] = *(const short8*)&Bs[(wn + i * 16 + l15) * 64 + cs];
                #pragma unroll
                for (int mi = 0; mi < 4; ++mi)
                    #pragma unroll
                    for (int ni = 0; ni < 4; ++ni)
                        acc[mi][ni] = __builtin_amdgcn_mfma_f32_16x16x32_bf16(
                            af[mi], bfr[ni], acc[mi][ni], 0, 0, 0);
            }
        }
    }

    const long coff = (long)bz * cstr;
    const int rb = m0 + wm + quad * 4;
    const int cbase = n0 + wn + l15;
    if (p.mode == 2) {
        #pragma unroll
        for (int ni = 0; ni < 4; ++ni) {
            const float bv = p.bias[cbase + ni * 16];
            #pragma unroll
            for (int mi = 0; mi < 4; ++mi)
                #pragma unroll
                for (int j = 0; j < 4; ++j)
                    Cf[coff + (long)(rb + mi * 16 + j) * ldc + cbase + ni * 16] =
                        tanhf(acc[mi][ni][j] + bv);
        }
    } else if (p.mode == 0) {
        #pragma unroll
        for (int ni = 0; ni < 4; ++ni)
            #pragma unroll
            for (int mi = 0; mi < 4; ++mi)
                #pragma unroll
                for (int j = 0; j < 4; ++j)
                    Cf[coff + (long)(rb + mi * 16 + j) * ldc + cbase + ni * 16] =
                        acc[mi][ni][j];
    } else {
        #pragma unroll
        for (int ni = 0; ni < 4; ++ni)
            #pragma unroll
            for (int mi = 0; mi < 4; ++mi)
                #pragma unroll
                for (int j = 0; j < 4; ++j)
                    p.Cb[coff + (long)(rb + mi * 16 + j) * ldc + cbase + ni * 16] =
                        f32_to_bf16(acc[mi][ni][j]);
    }
}

// ---------------- host ----------------
extern "C" void kernel_launch(void* const* d_in, const int* in_sizes, int n_in,
                              void* d_out, int out_size, void* d_ws, size_t ws_size,
                              hipStream_t stream) {
    const int BT = 80, L = 256, S = 512, H = 1024;
    const long NO    = (long)BT * L * H;   // 20971520
    const long NC1   = (long)8 * S * H;    // 4194304
    const long NW    = (long)H * 3 * H;    // 3145728
    const long NEXA  = (long)BT * L * L;   // 5242880
    const long NSETA = (long)BT * L * S;   // 10485760

    const float* X    = (const float*)d_in[0];
    const float* C0   = (const float*)d_in[1];
    const float* C1   = (const float*)d_in[2];
    const float* Wf   = (const float*)d_in[4];
    const float* bias = (const float*)d_in[5];

    float* out  = (float*)d_out;
    float* exa  = out + NO;
    float* seta = exa + NEXA;

    char* wsb = (char*)d_ws;
    size_t off = 0;
    auto alloc = [&](long nbytes) -> void* {
        void* p = (void*)(wsb + off);
        off += ((size_t)nbytes + 255) & ~(size_t)255;
        return p;
    };
    u16* Xhi  = (u16*)alloc(NO * 2);
    u16* Xlo  = (u16*)alloc(NO * 2);
    u16* C0hi = (u16*)alloc(NO * 2);
    u16* C0lo = (u16*)alloc(NO * 2);
    u16* C1hi = (u16*)alloc(NC1 * 2);
    u16* C1lo = (u16*)alloc(NC1 * 2);
    u16* Wb   = (u16*)alloc(NW * 2);
    u16* exab = (u16*)alloc(NEXA * 2);
    u16* setab= (u16*)alloc(NSETA * 2);
    // aliases (lifetimes disjoint by launch order):
    u16* C0T = C0lo;   // written by transpose after G12 (C0lo read in G12 part1 seg2)
    u16* C1T = C1lo;   // written by transpose after G12 (C1lo read in G12 part2 seg2)
    u16* exc = Xlo;    // written by GEMM3 (Xlo last read in G12)
    u16* setc = C0hi;  // written by GEMM4 (C0hi last read in G12)

    // --- prep ---
    split_kernel<<<(int)(NO / 4 / 256), 256, 0, stream>>>((const float4*)X, (ushort4*)Xhi, (ushort4*)Xlo, NO / 4);
    split_kernel<<<(int)(NO / 4 / 256), 256, 0, stream>>>((const float4*)C0, (ushort4*)C0hi, (ushort4*)C0lo, NO / 4);
    split_kernel<<<(int)(NC1 / 4 / 256), 256, 0, stream>>>((const float4*)C1, (ushort4*)C1hi, (ushort4*)C1lo, NC1 / 4);
    conv_kernel<<<(int)(NW / 4 / 256), 256, 0, stream>>>((const float4*)Wf, (ushort4*)Wb, NW / 4);

    // --- merged GEMM1+2: logits = X @ [C0 | set_ctx]^T (3-pass split, in-reg acc)
    //     part1 (n<2): ex logits -> exa; part2 (n in 2..5): set logits -> seta
    {
        GemmP p{};
        p.A[0] = Xhi;  p.A[1] = Xlo;  p.A[2] = Xhi;
        p.B[0]  = C0hi; p.B[1]  = C0hi; p.B[2]  = C0lo;
        p.B2[0] = C1hi; p.B2[1] = C1hi; p.B2[2] = C1lo;
        p.strideAb = (long)L * H;
        p.strideBb = (long)L * H;  p.strideB2b = (long)S * H;
        p.strideCb = (long)L * L;  p.strideC2b = (long)L * S;
        p.bdiv = 1; p.bdiv2 = 10;
        p.nseg = 3; p.Kper = H; p.lda = H; p.ldb = H; p.ldb2 = H;
        p.ldc = L; p.ldc2 = S; p.mode = 0;
        p.gx = 6; p.gy = 2; p.nx1 = 2;
        p.Cf = exa; p.Cf2 = seta;
        gemm_bt<<<dim3(6 * 2 * BT, 1, 1), 256, 0, stream>>>(p);
    }
    softmax_rows<4><<<BT * L / 4, 256, 0, stream>>>(exa, exab);
    softmax_rows<8><<<BT * L / 4, 256, 0, stream>>>(seta, setab);

    // --- transposes for PV B-operands ---
    transpose_u16<<<dim3(H / 32, L / 32, BT), dim3(32, 8), 0, stream>>>(C0hi, C0T, L, H);
    transpose_u16<<<dim3(H / 32, S / 32, 8), dim3(32, 8), 0, stream>>>(C1hi, C1T, S, H);

    // --- GEMM3: ex_c = ex_attn @ C0 -> bf16 exc ---
    {
        GemmP p{};
        p.A[0] = exab; p.B[0] = C0T;
        p.strideAb = (long)L * L; p.strideBb = (long)H * L; p.strideCb = (long)L * H;
        p.bdiv = 1; p.nseg = 1; p.Kper = L; p.lda = L; p.ldb = L; p.ldc = H; p.mode = 1;
        p.gx = 8; p.gy = 2; p.nx1 = 8;
        p.Cb = exc;
        gemm_bt<<<dim3(8 * 2 * BT, 1, 1), 256, 0, stream>>>(p);
    }
    // --- GEMM4: set_c = set_attn @ set_ctx -> bf16 setc ---
    {
        GemmP p{};
        p.A[0] = setab; p.B[0] = C1T;
        p.strideAb = (long)L * S; p.strideBb = (long)H * S; p.strideCb = (long)L * H;
        p.bdiv = 10; p.nseg = 1; p.Kper = S; p.lda = S; p.ldb = S; p.ldc = H; p.mode = 1;
        p.gx = 8; p.gy = 2; p.nx1 = 8;
        p.Cb = setc;
        gemm_bt<<<dim3(8 * 2 * BT, 1, 1), 256, 0, stream>>>(p);
    }
    // --- GEMM5: out = tanh(concat(X, ex_c, set_c) @ W^T + b), M = 20480 ---
    {
        GemmP p{};
        p.A[0] = Xhi; p.A[1] = exc; p.A[2] = setc;
        p.B[0] = Wb;  p.B[1] = Wb + 1024; p.B[2] = Wb + 2048;
        p.strideAb = 0; p.strideBb = 0; p.strideCb = 0;
        p.bdiv = 1; p.nseg = 3; p.Kper = H; p.lda = H; p.ldb = 3 * H; p.ldc = H; p.mode = 2;
        p.gx = 8; p.gy = BT * L / 128; p.nx1 = 8;
        p.Cf = out; p.bias = bias;
        gemm_bt<<<dim3(8 * (BT * L / 128), 1, 1), 256, 0, stream>>>(p);
    }
}